// Round 7
// baseline (158.712 us; speedup 1.0000x reference)
//
#include <hip/hip_runtime.h>

#define LOG2E 1.4426950408889634f

// DPP: CTRL=0x00/0x55/0xAA/0xFF = quad_perm broadcast lane 0/1/2/3 of quad;
// CTRL=0x114 = row_shr:4 (lane i <- lane i-4 within 16-lane row; low 4 -> 0).
template<int CTRL>
__device__ __forceinline__ float dppf(float v) {
    int r = __builtin_amdgcn_update_dpp(0, __float_as_int(v), CTRL, 0xF, 0xF, true);
    return __int_as_float(r);
}

// compile-time component pick from a float4 buffer (I is constant after unroll)
#define AV(B, I) ((I) % 4 == 0 ? (B)[(I)/4].x : (I) % 4 == 1 ? (B)[(I)/4].y \
                 : (I) % 4 == 2 ? (B)[(I)/4].z : (B)[(I)/4].w)

struct LaneW {
    // Gate pre-activations pre-scaled by msc = (g-lane ? -2L : -L) so that
    // r = rcp(1+exp2(z)) gives sigma(y) on sigma lanes and sigma(2y) on g lane.
    float vb, v0, v1, v2, v3;   // msc * (bias, V[0..3][g])
    float wcx;                  // L1: msc*W1[g] (x-input); L2: unused
    float uc;                   // msc*U[g]   (own-h recurrent)
    float wc2;                  // L2: msc*W2[g] (h1 input); L1: 0
    float fw, fb;
    bool isl2;
};

// One fused call. L1 lanes (quads 0,2) compute step tau; L2 lanes (quads 1,3)
// compute step tau-2 (2-call lag; cross-layer handoff fully off-chain via
// carried regs voc/r2c). h = vo*(2*r2-1), C = 2L*c. The zero state has the
// exact fixed-point encoding (vo=.5 or 0, r2=.5, C=0) under zero inputs.
__device__ __forceinline__ float lstm_step2(
    float a0, float a1, float a2, float a3, float xv,
    const LaneW& w, float& C, float& vo, float& r2,
    float& zv1, float& zv2, float& voc, float& r2c)
{
    // ---- off-chain: weather dot, delay line, folded recurrent terms ----
    float zv = fmaf(a3, w.v3, fmaf(a2, w.v2, fmaf(a1, w.v1, fmaf(a0, w.v0, w.vb))));
    float zb = w.isl2 ? zv2 : fmaf(xv, w.wcx, zv);  // L2: 2-call-delayed dot
    zv2 = zv1; zv1 = zv;
    float tU = w.uc * vo;            // uc*h = ku*r2 - tU, ku = 2*tU
    float ku = tU + tU;
    float tW = w.wc2 * voc;          // cross-layer (L1: wc2=0)
    float kw = tW + tW;
    float q  = fmaf(kw, r2c, (zb - tU) - tW);
    // handoff for NEXT call: dpp of ENTRY state (off the per-step cycle)
    float nvoc = dppf<0x114>(vo);
    float nr2c = dppf<0x114>(r2);
    // ---- chain: z -> r -> C -> r2 ----
    float z  = fmaf(ku, r2, q);
    float e  = __builtin_amdgcn_exp2f(z);
    float r  = __builtin_amdgcn_rcpf(1.0f + e);
    float d3 = dppf<0x55>(r);                  // f       (sigma)
    float d2 = dppf<0xAA>(r);                  // sigma_g (tanh encoded)
    float d1 = dppf<0x00>(r);                  // i       (sigma)
    float t1 = d3 * C;
    float t2 = fmaf(4.0f * LOG2E, d2, -2.0f * LOG2E);   // = 2L*g
    vo       = dppf<0xFF>(r);                  // o (state update)
    C        = fmaf(d1, t2, t1);
    float E2 = __builtin_amdgcn_exp2f(-C);     // neg = free src modifier
    r2       = __builtin_amdgcn_rcpf(1.0f + E2);
    voc = nvoc; r2c = nr2c;
    // ---- off-chain: h, FC ----
    float tm = fmaf(2.0f, r2, -1.0f);
    float h  = vo * tm;
    return fmaf(h, w.fw, w.fb);
}

__global__ __launch_bounds__(256, 4) void pew_lstm_kernel(
    const float* __restrict__ input,
    const float* __restrict__ W1, const float* __restrict__ U1,
    const float* __restrict__ V1, const float* __restrict__ b1,
    const float* __restrict__ W2, const float* __restrict__ U2,
    const float* __restrict__ V2, const float* __restrict__ b2,
    const float* __restrict__ fcW, const float* __restrict__ fcb,
    float* __restrict__ out, int B)
{
    const int lane = threadIdx.x & 63;
    const int tid  = blockIdx.x * blockDim.x + threadIdx.x;
    const int gid  = tid >> 3;            // 8-lane group
    const int wv   = gid >> 3;            // wave index (chunk uniform per wave)
    const int chunk = wv & 3;             // 4 time chunks per sequence
    const int seq   = ((wv >> 2) << 3) + (gid & 7);
    if (seq >= B) return;
    const bool isl2 = (lane & 4) != 0;
    const int  g    = lane & 3;

    LaneW w;
    w.isl2 = isl2;
    const float* Wx = isl2 ? W2 : W1;
    const float* Ux = isl2 ? U2 : U1;
    const float* Vx = isl2 ? V2 : V1;
    const float* bx = isl2 ? b2 : b1;
    const bool istanh = (g == 2);
    const float msc = istanh ? (-2.0f * LOG2E) : (-LOG2E);
    w.wcx = msc * Wx[g]; w.uc = msc * Ux[g]; w.vb = msc * bx[g];
    w.v0 = msc * Vx[g]; w.v1 = msc * Vx[4 + g];
    w.v2 = msc * Vx[8 + g]; w.v3 = msc * Vx[12 + g];
    w.wc2 = isl2 ? w.wcx : 0.0f;
    w.fw = fcW[0]; w.fb = fcb[0];

    // chunk geometry: outputs [s0, s0+256); warmup W=64 (chunk 0: none)
    const int s0 = chunk << 8;
    const int Wm = chunk ? 64 : 0;
    const int t0 = s0 - Wm;                  // multiple of 16
    const int npair = (Wm + 256) >> 4;       // 16 or 20 pairs of 8-call blocks
    const int mpflush = chunk ? 5 : 1;       // first pair allowed to flush

    const float4* __restrict__ p  =
        reinterpret_cast<const float4*>(input + (size_t)seq * 5120 + (size_t)t0 * 5);
    float4* __restrict__ op = reinterpret_cast<float4*>(out + (size_t)seq * 1024);
    const bool stlane = (lane & 7) == 4;     // one L2 lane per group stores

    float4 bufA[10], bufB[10];               // 8 calls per buffer (40 floats)
#pragma unroll
    for (int q2 = 0; q2 < 10; q2++) bufA[q2] = p[q2];
#pragma unroll
    for (int q2 = 0; q2 < 10; q2++) bufB[q2] = p[10 + q2];

    // zero-state encoding (exact fixed point under zero inputs)
    float C = 0.f, vo = 0.f, r2 = 0.5f;
    float zv1 = 0.f, zv2 = 0.f, voc = 0.f, r2c = 0.5f;
    float ro[16];                            // output ring, flush 16 at a time

#pragma unroll 1
    for (int mp = 0; mp < npair; mp++) {
        // bufA: calls j = 16mp + jj   (u = t0 + j - 2; slot = (j-2)&15)
#pragma unroll
        for (int jj = 0; jj < 8; jj++) {
            float res = lstm_step2(AV(bufA,5*jj+0), AV(bufA,5*jj+1), AV(bufA,5*jj+2),
                                   AV(bufA,5*jj+3), AV(bufA,5*jj+4),
                                   w, C, vo, r2, zv1, zv2, voc, r2c);
            if (jj >= 2) ro[jj - 2] = res; else ro[14 + jj] = res;
            if (jj == 1 && mp >= mpflush && stlane) {
                int ob = (t0 + 16 * mp - 16) >> 2;       // block u-16..u-1 -> 4xfloat4
                op[ob+0] = make_float4(ro[0], ro[1], ro[2], ro[3]);
                op[ob+1] = make_float4(ro[4], ro[5], ro[6], ro[7]);
                op[ob+2] = make_float4(ro[8], ro[9], ro[10], ro[11]);
                op[ob+3] = make_float4(ro[12], ro[13], ro[14], ro[15]);
            }
        }
        if (mp < npair - 1) {
#pragma unroll
            for (int q2 = 0; q2 < 10; q2++) bufA[q2] = p[20 * mp + 20 + q2];
        }
        // bufB: calls j = 16mp + 8 + jj  (slot = jj + 6)
#pragma unroll
        for (int jj = 0; jj < 8; jj++) {
            float res = lstm_step2(AV(bufB,5*jj+0), AV(bufB,5*jj+1), AV(bufB,5*jj+2),
                                   AV(bufB,5*jj+3), AV(bufB,5*jj+4),
                                   w, C, vo, r2, zv1, zv2, voc, r2c);
            ro[jj + 6] = res;
        }
        if (mp < npair - 1) {
#pragma unroll
            for (int q2 = 0; q2 < 10; q2++) bufB[q2] = p[20 * mp + 30 + q2];
        }
    }
    // drain: 2 zero-input calls finish L2 steps s0+254, s0+255
    {
        float res = lstm_step2(0.f, 0.f, 0.f, 0.f, 0.f,
                               w, C, vo, r2, zv1, zv2, voc, r2c);
        ro[14] = res;
        res = lstm_step2(0.f, 0.f, 0.f, 0.f, 0.f,
                         w, C, vo, r2, zv1, zv2, voc, r2c);
        ro[15] = res;
        if (stlane) {
            int ob = (s0 + 240) >> 2;
            op[ob+0] = make_float4(ro[0], ro[1], ro[2], ro[3]);
            op[ob+1] = make_float4(ro[4], ro[5], ro[6], ro[7]);
            op[ob+2] = make_float4(ro[8], ro[9], ro[10], ro[11]);
            op[ob+3] = make_float4(ro[12], ro[13], ro[14], ro[15]);
        }
    }
}

extern "C" void kernel_launch(void* const* d_in, const int* in_sizes, int n_in,
                              void* d_out, int out_size, void* d_ws, size_t ws_size,
                              hipStream_t stream) {
    const float* input = (const float*)d_in[0];
    const float* W1 = (const float*)d_in[1];
    const float* U1 = (const float*)d_in[2];
    const float* V1 = (const float*)d_in[3];
    const float* b1 = (const float*)d_in[4];
    const float* W2 = (const float*)d_in[5];
    const float* U2 = (const float*)d_in[6];
    const float* V2 = (const float*)d_in[7];
    const float* b2 = (const float*)d_in[8];
    const float* fcW = (const float*)d_in[9];
    const float* fcb = (const float*)d_in[10];
    float* out = (float*)d_out;

    int B = in_sizes[0] / (1024 * 5);
    long long threads_total = (long long)B * 32;   // 8 lanes * 4 chunks per sequence
    int blocks = (int)((threads_total + 255) / 256);
    hipLaunchKernelGGL(pew_lstm_kernel, dim3(blocks), dim3(256), 0, stream,
                       input, W1, U1, V1, b1, W2, U2, V2, b2, fcW, fcb, out, B);
}

// Round 8
// 86.987 us; speedup vs baseline: 1.8245x; 1.8245x over previous
//
#include <hip/hip_runtime.h>

#define LOG2E 1.4426950408889634f

// DPP: CTRL=0x00/0x55/0xAA/0xFF = quad_perm broadcast lane 0/1/2/3 of quad;
// CTRL=0x114 = row_shr:4 (lane i <- lane i-4 within 16-lane row; low 4 -> 0).
template<int CTRL>
__device__ __forceinline__ float dppf(float v) {
    int r = __builtin_amdgcn_update_dpp(0, __float_as_int(v), CTRL, 0xF, 0xF, true);
    return __int_as_float(r);
}

// async global->LDS DMA, 4 B per lane (64 contiguous dwords per instruction)
__device__ __forceinline__ void gload_lds(const float* g, float* l) {
    __builtin_amdgcn_global_load_lds(
        (const __attribute__((address_space(1))) void*)g,
        (__attribute__((address_space(3))) void*)l, 4, 0, 0);
}

struct LaneW {
    // Gate pre-activations pre-scaled by msc = (g-lane ? -2L : -L) so that
    // r = rcp(1+exp2(z)) gives sigma(y) on sigma lanes and sigma(2y) on g lane.
    float vb, v0, v1, v2, v3;   // msc * (bias, V[0..3][g])
    float wcx;                  // L1: msc*W1[g] (x-input); L2: unused
    float uc;                   // msc*U[g]   (own-h recurrent)
    float wc2;                  // L2: msc*W2[g] (h1 input); L1: 0
    float fw, fb;
    bool isl2;
};

// One fused call. L1 lanes (quads 0,2) compute step tau; L2 lanes (quads 1,3)
// compute step tau-2 (2-call lag; cross-layer handoff fully off-chain via
// carried regs voc/r2c). h = vo*(2*r2-1), C = 2L*c. Zero state: vo=0, r2=.5,
// C=0 is an exact fixed point under zero inputs.
__device__ __forceinline__ float lstm_step2(
    float a0, float a1, float a2, float a3, float xv,
    const LaneW& w, float& C, float& vo, float& r2,
    float& zv1, float& zv2, float& voc, float& r2c)
{
    // ---- off-chain: weather dot, delay line, folded recurrent terms ----
    float zv = fmaf(a3, w.v3, fmaf(a2, w.v2, fmaf(a1, w.v1, fmaf(a0, w.v0, w.vb))));
    float zb = w.isl2 ? zv2 : fmaf(xv, w.wcx, zv);  // L2: 2-call-delayed dot
    zv2 = zv1; zv1 = zv;
    float tU = w.uc * vo;            // uc*h = ku*r2 - tU, ku = 2*tU
    float ku = tU + tU;
    float tW = w.wc2 * voc;          // cross-layer (L1: wc2=0)
    float kw = tW + tW;
    float q  = fmaf(kw, r2c, (zb - tU) - tW);
    // handoff for NEXT call: dpp of ENTRY state (off the per-step cycle)
    float nvoc = dppf<0x114>(vo);
    float nr2c = dppf<0x114>(r2);
    // ---- chain: z -> r -> C -> r2 ----
    float z  = fmaf(ku, r2, q);
    float e  = __builtin_amdgcn_exp2f(z);
    float r  = __builtin_amdgcn_rcpf(1.0f + e);
    float d3 = dppf<0x55>(r);                  // f       (sigma)
    float d2 = dppf<0xAA>(r);                  // sigma_g (tanh encoded)
    float d1 = dppf<0x00>(r);                  // i       (sigma)
    float t1 = d3 * C;
    float t2 = fmaf(4.0f * LOG2E, d2, -2.0f * LOG2E);   // = 2L*g
    vo       = dppf<0xFF>(r);                  // o (state update)
    C        = fmaf(d1, t2, t1);
    float E2 = __builtin_amdgcn_exp2f(-C);     // neg = free src modifier
    r2       = __builtin_amdgcn_rcpf(1.0f + E2);
    voc = nvoc; r2c = nr2c;
    // ---- off-chain: h, FC ----
    float tm = fmaf(2.0f, r2, -1.0f);
    float h  = vo * tm;
    return fmaf(h, w.fw, w.fb);
}

__global__ __launch_bounds__(256, 4) void pew_lstm_kernel(
    const float* __restrict__ input,
    const float* __restrict__ W1, const float* __restrict__ U1,
    const float* __restrict__ V1, const float* __restrict__ b1,
    const float* __restrict__ W2, const float* __restrict__ U2,
    const float* __restrict__ V2, const float* __restrict__ b2,
    const float* __restrict__ fcW, const float* __restrict__ fcb,
    float* __restrict__ out, int B)
{
    // per-wave staging: [wave][dbuf][16 calls * 5 dw * 8 rows] = 20 KiB/block
    __shared__ float lds[4][2][640];

    const int lane  = threadIdx.x & 63;
    const int wslot = threadIdx.x >> 6;        // wave in block = chunk (0..3)
    const int chunk = wslot;
    const int seq0  = blockIdx.x << 3;         // 8 sequences per block
    const int grp   = lane >> 3;
    const int seq   = seq0 + grp;
    if (seq >= B) return;
    const bool isl2 = (lane & 4) != 0;
    const int  g    = lane & 3;

    LaneW w;
    w.isl2 = isl2;
    const float* Wx = isl2 ? W2 : W1;
    const float* Ux = isl2 ? U2 : U1;
    const float* Vx = isl2 ? V2 : V1;
    const float* bx = isl2 ? b2 : b1;
    const bool istanh = (g == 2);
    const float msc = istanh ? (-2.0f * LOG2E) : (-LOG2E);
    w.wcx = msc * Wx[g]; w.uc = msc * Ux[g]; w.vb = msc * bx[g];
    w.v0 = msc * Vx[g]; w.v1 = msc * Vx[4 + g];
    w.v2 = msc * Vx[8 + g]; w.v3 = msc * Vx[12 + g];
    w.wc2 = isl2 ? w.wcx : 0.0f;
    w.fw = fcW[0]; w.fb = fcb[0];

    // chunk geometry: outputs [s0, s0+256); warmup 64 steps (chunk 0: none)
    const int s0  = chunk << 8;
    const int Wm  = chunk ? 64 : 0;
    const int t0  = s0 - Wm;                   // multiple of 16
    const int nsb = (Wm + 256) >> 4;           // superblocks of 16 calls: 16 / 20
    const int sbflush = chunk ? 5 : 1;

    // per-lane global byte offsets for the 5-instruction DMA pattern:
    // flat dw f = 64*i + lane over a 16-call slab; row r = f/80, d = f%80.
    int off5[5];
#pragma unroll
    for (int i = 0; i < 5; i++) {
        int f = 64 * i + lane;
        int r = f / 80;
        int d = f - 80 * r;
        off5[i] = r * 20480 + d * 4;           // row pitch 1024*5*4 B
    }

    const char* __restrict__ gseq = (const char*)input + (size_t)seq0 * 20480;
    float* lbuf0 = &lds[wslot][0][0];
    float* lbuf1 = &lds[wslot][1][0];
    const int rowbase = grp * 80;              // my group's row in the buffer

    float* __restrict__ opf = out + (size_t)seq * 1024;
    const bool stlane = (lane & 7) == 4;       // one L2 lane per group stores

    // prologue: DMA superblock 0 into buf0
    {
        const char* gsb = gseq + (size_t)t0 * 20;
#pragma unroll
        for (int i = 0; i < 10; i++)
            gload_lds((const float*)(gsb + off5[i % 5] + (i / 5) * 81920),
                      lbuf0 + i * 64);
    }

    float C = 0.f, vo = 0.f, r2 = 0.5f;
    float zv1 = 0.f, zv2 = 0.f, voc = 0.f, r2c = 0.5f;
    float ro[16];                              // output ring, flush 16 at a time

#pragma unroll 1
    for (int sb = 0; sb < nsb; sb++) {
        float* cb = (sb & 1) ? lbuf1 : lbuf0;
        float* nb = (sb & 1) ? lbuf0 : lbuf1;
        if (sb + 1 < nsb) {
            const char* gsb = gseq + (size_t)(t0 + 16 * (sb + 1)) * 20;
#pragma unroll
            for (int i = 0; i < 10; i++)
                gload_lds((const float*)(gsb + off5[i % 5] + (i / 5) * 81920),
                          nb + i * 64);
            // wait for CURRENT buffer's 10 loads; keep next 10 in flight
            asm volatile("s_waitcnt vmcnt(10)" ::: "memory");
        } else {
            asm volatile("s_waitcnt vmcnt(0)" ::: "memory");
        }
        __builtin_amdgcn_sched_barrier(0);
        const float* mrow = cb + rowbase;
#pragma unroll
        for (int jj = 0; jj < 16; jj++) {
            float a0 = mrow[5*jj+0], a1 = mrow[5*jj+1], a2 = mrow[5*jj+2];
            float a3 = mrow[5*jj+3], xv = mrow[5*jj+4];
            float res = lstm_step2(a0, a1, a2, a3, xv,
                                   w, C, vo, r2, zv1, zv2, voc, r2c);
            if (jj >= 2) ro[jj - 2] = res; else ro[14 + jj] = res;
            if (jj == 1 && sb >= sbflush && stlane) {
                float4* op4 = (float4*)(opf + (t0 + 16 * sb - 16));
                op4[0] = make_float4(ro[0],  ro[1],  ro[2],  ro[3]);
                op4[1] = make_float4(ro[4],  ro[5],  ro[6],  ro[7]);
                op4[2] = make_float4(ro[8],  ro[9],  ro[10], ro[11]);
                op4[3] = make_float4(ro[12], ro[13], ro[14], ro[15]);
            }
        }
    }
    // drain: 2 zero-input calls finish L2 steps s0+254, s0+255, then flush
    {
        float res = lstm_step2(0.f, 0.f, 0.f, 0.f, 0.f,
                               w, C, vo, r2, zv1, zv2, voc, r2c);
        ro[14] = res;
        res = lstm_step2(0.f, 0.f, 0.f, 0.f, 0.f,
                         w, C, vo, r2, zv1, zv2, voc, r2c);
        ro[15] = res;
        if (stlane) {
            float4* op4 = (float4*)(opf + (s0 + 240));
            op4[0] = make_float4(ro[0],  ro[1],  ro[2],  ro[3]);
            op4[1] = make_float4(ro[4],  ro[5],  ro[6],  ro[7]);
            op4[2] = make_float4(ro[8],  ro[9],  ro[10], ro[11]);
            op4[3] = make_float4(ro[12], ro[13], ro[14], ro[15]);
        }
    }
}

extern "C" void kernel_launch(void* const* d_in, const int* in_sizes, int n_in,
                              void* d_out, int out_size, void* d_ws, size_t ws_size,
                              hipStream_t stream) {
    const float* input = (const float*)d_in[0];
    const float* W1 = (const float*)d_in[1];
    const float* U1 = (const float*)d_in[2];
    const float* V1 = (const float*)d_in[3];
    const float* b1 = (const float*)d_in[4];
    const float* W2 = (const float*)d_in[5];
    const float* U2 = (const float*)d_in[6];
    const float* V2 = (const float*)d_in[7];
    const float* b2 = (const float*)d_in[8];
    const float* fcW = (const float*)d_in[9];
    const float* fcb = (const float*)d_in[10];
    float* out = (float*)d_out;

    int B = in_sizes[0] / (1024 * 5);
    int blocks = (B + 7) / 8;                  // 8 seqs * 4 chunks per 256-thr block
    hipLaunchKernelGGL(pew_lstm_kernel, dim3(blocks), dim3(256), 0, stream,
                       input, W1, U1, V1, b1, W2, U2, V2, b2, fcW, fcb, out, B);
}

// Round 9
// 78.733 us; speedup vs baseline: 2.0158x; 1.1048x over previous
//
#include <hip/hip_runtime.h>

#define LOG2E 1.4426950408889634f

// DPP: CTRL=0x00/0x55/0xAA/0xFF = quad_perm broadcast lane 0/1/2/3 of quad;
// CTRL=0x114 = row_shr:4 (lane i <- lane i-4 within 16-lane row; low 4 -> 0).
template<int CTRL>
__device__ __forceinline__ float dppf(float v) {
    int r = __builtin_amdgcn_update_dpp(0, __float_as_int(v), CTRL, 0xF, 0xF, true);
    return __int_as_float(r);
}

// async global->LDS DMA, 4 B per lane (64 contiguous dwords per instruction)
__device__ __forceinline__ void gload_lds(const float* g, float* l) {
    __builtin_amdgcn_global_load_lds(
        (const __attribute__((address_space(1))) void*)g,
        (__attribute__((address_space(3))) void*)l, 4, 0, 0);
}

struct LaneW {
    // Gate pre-activations pre-scaled by msc = (g-lane ? -2L : -L) so that
    // r = rcp(1+exp2(z)) gives sigma(y) on sigma lanes and sigma(2y) on g lane.
    float vb, v0, v1, v2, v3;   // msc * (bias, V[0..3][g])
    float wcx;                  // L1: msc*W1[g] (x-input); L2: unused (0 path)
    float uc;                   // msc*U[g]   (own-h recurrent)
    float wc2;                  // L2: msc*W2[g] (h1 input); L1: 0
    float fw, fb;
    bool isl2;
};

// One fused call, h-materialized form (issue-count optimized; chain depth is
// hidden by 4 waves/SIMD). L1 lanes (quads 0,2) process step tau; L2 lanes
// (quads 1,3) process step tau-2. hx consumed at call tau = dpp of entry-h at
// call tau-1 = h1(tau-2) (L2's current-step x-input). C = 2L*c.
// Zero state (h=0, C=0, hx=0, zv*=0) is exact.
__device__ __forceinline__ float lstm_step3(
    float a0, float a1, float a2, float a3, float xv,
    const LaneW& w, float& C, float& h, float& hx,
    float& zv1, float& zv2)
{
    float nhx = dppf<0x114>(h);              // entry h -> hx for NEXT call
    float zv = fmaf(a3, w.v3, fmaf(a2, w.v2, fmaf(a1, w.v1, fmaf(a0, w.v0, w.vb))));
    float zb = w.isl2 ? zv2 : fmaf(xv, w.wcx, zv);  // L2: 2-call-delayed dot
    zv2 = zv1; zv1 = zv;
    float zc = fmaf(w.wc2, hx, zb);          // cross-layer term (L1: wc2=0)
    float z  = fmaf(w.uc, h, zc);            // own recurrent term
    float e  = __builtin_amdgcn_exp2f(z);
    float r  = __builtin_amdgcn_rcpf(1.0f + e);
    float d3 = dppf<0x55>(r);                // f
    float d2 = dppf<0xAA>(r);                // sigma_g (tanh encoded)
    float d1 = dppf<0x00>(r);                // i
    float vo = dppf<0xFF>(r);                // o
    float t1 = d3 * C;
    float t2 = fmaf(4.0f * LOG2E, d2, -2.0f * LOG2E);   // = 2L*g
    C        = fmaf(d1, t2, t1);             // C = 2L*c
    float E2 = __builtin_amdgcn_exp2f(-C);   // neg = free src modifier
    float r2 = __builtin_amdgcn_rcpf(1.0f + E2);
    float tm = fmaf(2.0f, r2, -1.0f);        // tanh(c)
    h  = vo * tm;
    hx = nhx;
    return fmaf(h, w.fw, w.fb);
}

__global__ __launch_bounds__(256, 4) void pew_lstm_kernel(
    const float* __restrict__ input,
    const float* __restrict__ W1, const float* __restrict__ U1,
    const float* __restrict__ V1, const float* __restrict__ b1,
    const float* __restrict__ W2, const float* __restrict__ U2,
    const float* __restrict__ V2, const float* __restrict__ b2,
    const float* __restrict__ fcW, const float* __restrict__ fcb,
    float* __restrict__ out, int B)
{
    // per-wave staging: [wave][dbuf][8 rows * 81 dw + spill] = 22528 B/block.
    // Row stride 81 dw -> group g reads bank 17g mod 32: all distinct,
    // conflict-free broadcasts (fixes R8's 4-way conflict at stride 80).
    __shared__ float lds[4][2][704];

    const int lane  = threadIdx.x & 63;
    const int wslot = threadIdx.x >> 6;        // wave in block = chunk (0..3)
    const int chunk = wslot;
    const int seq0  = blockIdx.x << 3;         // 8 sequences per block
    const int grp   = lane >> 3;
    const int seq   = seq0 + grp;
    if (seq >= B) return;
    const bool isl2 = (lane & 4) != 0;
    const int  g    = lane & 3;

    LaneW w;
    w.isl2 = isl2;
    const float* Wx = isl2 ? W2 : W1;
    const float* Ux = isl2 ? U2 : U1;
    const float* Vx = isl2 ? V2 : V1;
    const float* bx = isl2 ? b2 : b1;
    const bool istanh = (g == 2);
    const float msc = istanh ? (-2.0f * LOG2E) : (-LOG2E);
    w.wcx = msc * Wx[g]; w.uc = msc * Ux[g]; w.vb = msc * bx[g];
    w.v0 = msc * Vx[g]; w.v1 = msc * Vx[4 + g];
    w.v2 = msc * Vx[8 + g]; w.v3 = msc * Vx[12 + g];
    w.wc2 = isl2 ? w.wcx : 0.0f;
    w.fw = fcW[0]; w.fb = fcb[0];

    // chunk geometry: outputs [s0, s0+256); warmup 64 steps (chunk 0: none)
    const int s0  = chunk << 8;
    const int Wm  = chunk ? 64 : 0;
    const int t0  = s0 - Wm;                   // multiple of 16
    const int nsb = (Wm + 256) >> 4;           // superblocks of 16 calls: 16 / 20
    const int sbflush = chunk ? 5 : 1;

    // per-lane global byte offsets for the 11-instruction DMA pattern:
    // LDS linear dw L = 64*i + lane maps to row r = L/81, col d = L-81r;
    // d==80 / L>=648 are pad slots (source clamped to 0, data unused).
    int off11[11];
#pragma unroll
    for (int i = 0; i < 11; i++) {
        int L = 64 * i + lane;
        int r = L / 81;
        int d = L - 81 * r;
        off11[i] = (L < 648 && d < 80) ? (r * 20480 + d * 4) : 0;
    }

    const char* __restrict__ gseq = (const char*)input + (size_t)seq0 * 20480;
    float* lbuf0 = &lds[wslot][0][0];
    float* lbuf1 = &lds[wslot][1][0];
    const int rowbase = grp * 81;              // padded row stride

    float* __restrict__ opf = out + (size_t)seq * 1024;
    const bool stlane = (lane & 7) == 4;       // one L2 lane per group stores

    // prologue: DMA superblock 0 into buf0
    {
        const char* gsb = gseq + (size_t)t0 * 20;
#pragma unroll
        for (int i = 0; i < 11; i++)
            gload_lds((const float*)(gsb + off11[i]), lbuf0 + i * 64);
    }

    float C = 0.f, h = 0.f, hx = 0.f, zv1 = 0.f, zv2 = 0.f;
    float ro[16];                              // output ring, flush 16 at a time

#pragma unroll 1
    for (int sb = 0; sb < nsb; sb++) {
        float* cb = (sb & 1) ? lbuf1 : lbuf0;
        float* nb = (sb & 1) ? lbuf0 : lbuf1;
        if (sb + 1 < nsb) {
            const char* gsb = gseq + (size_t)(t0 + 16 * (sb + 1)) * 20;
#pragma unroll
            for (int i = 0; i < 11; i++)
                gload_lds((const float*)(gsb + off11[i]), nb + i * 64);
            // wait for CURRENT buffer's 11 loads; keep next 11 in flight
            asm volatile("s_waitcnt vmcnt(11)" ::: "memory");
        } else {
            asm volatile("s_waitcnt vmcnt(0)" ::: "memory");
        }
        __builtin_amdgcn_sched_barrier(0);
        const float* mrow = cb + rowbase;
#pragma unroll
        for (int jj = 0; jj < 16; jj++) {
            float a0 = mrow[5*jj+0], a1 = mrow[5*jj+1], a2 = mrow[5*jj+2];
            float a3 = mrow[5*jj+3], xv = mrow[5*jj+4];
            float res = lstm_step3(a0, a1, a2, a3, xv,
                                   w, C, h, hx, zv1, zv2);
            if (jj >= 2) ro[jj - 2] = res; else ro[14 + jj] = res;
            if (jj == 1 && sb >= sbflush && stlane) {
                float4* op4 = (float4*)(opf + (t0 + 16 * sb - 16));
                op4[0] = make_float4(ro[0],  ro[1],  ro[2],  ro[3]);
                op4[1] = make_float4(ro[4],  ro[5],  ro[6],  ro[7]);
                op4[2] = make_float4(ro[8],  ro[9],  ro[10], ro[11]);
                op4[3] = make_float4(ro[12], ro[13], ro[14], ro[15]);
            }
        }
    }
    // drain: 2 zero-input calls finish L2 steps s0+254, s0+255, then flush
    {
        float res = lstm_step3(0.f, 0.f, 0.f, 0.f, 0.f, w, C, h, hx, zv1, zv2);
        ro[14] = res;
        res = lstm_step3(0.f, 0.f, 0.f, 0.f, 0.f, w, C, h, hx, zv1, zv2);
        ro[15] = res;
        if (stlane) {
            float4* op4 = (float4*)(opf + (s0 + 240));
            op4[0] = make_float4(ro[0],  ro[1],  ro[2],  ro[3]);
            op4[1] = make_float4(ro[4],  ro[5],  ro[6],  ro[7]);
            op4[2] = make_float4(ro[8],  ro[9],  ro[10], ro[11]);
            op4[3] = make_float4(ro[12], ro[13], ro[14], ro[15]);
        }
    }
}

extern "C" void kernel_launch(void* const* d_in, const int* in_sizes, int n_in,
                              void* d_out, int out_size, void* d_ws, size_t ws_size,
                              hipStream_t stream) {
    const float* input = (const float*)d_in[0];
    const float* W1 = (const float*)d_in[1];
    const float* U1 = (const float*)d_in[2];
    const float* V1 = (const float*)d_in[3];
    const float* b1 = (const float*)d_in[4];
    const float* W2 = (const float*)d_in[5];
    const float* U2 = (const float*)d_in[6];
    const float* V2 = (const float*)d_in[7];
    const float* b2 = (const float*)d_in[8];
    const float* fcW = (const float*)d_in[9];
    const float* fcb = (const float*)d_in[10];
    float* out = (float*)d_out;

    int B = in_sizes[0] / (1024 * 5);
    int blocks = (B + 7) / 8;                  // 8 seqs * 4 chunks per 256-thr block
    hipLaunchKernelGGL(pew_lstm_kernel, dim3(blocks), dim3(256), 0, stream,
                       input, W1, U1, V1, b1, W2, U2, V2, b2, fcW, fcb, out, B);
}